// Round 2
// baseline (2632.224 us; speedup 1.0000x reference)
//
#include <hip/hip_runtime.h>

#define NCB 9
#define KCB 1024
#define CD 8
#define DD 64
#define TT 32768
#define BB 4

#define ZQ_SZ (BB*DD*TT)              // 8388608
#define CODES_OFF ZQ_SZ
#define CODES_SZ (BB*NCB*TT)          // 1179648
#define LAT_OFF (CODES_OFF + CODES_SZ)
#define LAT_SZ (BB*NCB*CD*TT)         // 9437184
#define LOSS_OFF (LAT_OFF + LAT_SZ)   // 19005440

// ---- d_ws byte layout ----
// cbn32   [73728 f]      @ 0
// scbk32  [9216 f]       @ 294912
// loss_part [512 d]      @ 331776
// cbn64   [73728 d]      @ 335872
// scbk64  [9216 d]       @ 925696
// Win64   [4608 d]       @ 999424
// Wout64  [4608 d]       @ 1036288
// bin64   [72 d]         @ 1073152
// bout64  [576 d]        @ 1073728   (end 1078336)
#define OFF_SCBK32   294912
#define OFF_LOSSPART 331776
#define OFF_CBN64    335872
#define OFF_SCBK64   925696
#define OFF_WIN64    999424
#define OFF_WOUT64   1036288
#define OFF_BIN64    1073152
#define OFF_BOUT64   1073728

__global__ void prep_cb(const float* __restrict__ cb,
                        float* __restrict__ cbn32, float* __restrict__ scbk32,
                        double* __restrict__ cbn64, double* __restrict__ scbk64) {
  int r = blockIdx.x * blockDim.x + threadIdx.x;
  if (r >= NCB * KCB) return;
  double v[CD], s = 0.0;
#pragma unroll
  for (int c = 0; c < CD; c++) { v[c] = (double)cb[r*CD + c]; s += v[c]*v[c]; }
  double den = fmax(sqrt(s), 1e-12);
  double s2 = 0.0;
#pragma unroll
  for (int c = 0; c < CD; c++) {
    double o = v[c] / den;
    cbn64[r*CD + c] = o;
    cbn32[r*CD + c] = (float)o;
    s2 += o*o;
  }
  scbk64[r] = s2;
  scbk32[r] = (float)s2;
}

__global__ void prep_w(const float* __restrict__ W_in, const float* __restrict__ b_in,
                       const float* __restrict__ W_out, const float* __restrict__ b_out,
                       double* __restrict__ Win64, double* __restrict__ bin64,
                       double* __restrict__ Wout64, double* __restrict__ bout64) {
  int i = blockIdx.x * blockDim.x + threadIdx.x;
  if (i < NCB*CD*DD) Win64[i]  = (double)W_in[i];
  if (i < NCB*CD*DD) Wout64[i] = (double)W_out[i];
  if (i < NCB*CD)    bin64[i]  = (double)b_in[i];
  if (i < NCB*DD)    bout64[i] = (double)b_out[i];
}

__global__ __launch_bounds__(256, 2) void rvq_kernel(
    const float* __restrict__ x,
    const float* __restrict__ cb,
    const double* __restrict__ Win64,
    const double* __restrict__ bin64,
    const double* __restrict__ Wout64,
    const double* __restrict__ bout64,
    const float* __restrict__ cbn32,
    const float* __restrict__ scbk32,
    const double* __restrict__ cbn64,
    const double* __restrict__ scbk64,
    float* __restrict__ out,
    double* __restrict__ loss_part) {
  const int tid = blockIdx.x * 256 + threadIdx.x;
  const int b = tid / TT;          // uniform per block (TT % 256 == 0)
  const int t = tid - b * TT;

  // residual chain in f64 — must track the f64 golden reference end-to-end
  double r[DD];
#pragma unroll
  for (int d = 0; d < DD; d++) r[d] = (double)x[(b*DD + d)*TT + t];

  double lacc = 0.0;

  for (int i = 0; i < NCB; i++) {
    // ---- in_proj (f64): z_e = W_in[i] @ r + b_in[i]
    double ze[CD];
#pragma unroll
    for (int c = 0; c < CD; c++) {
      double acc = bin64[i*CD + c];
#pragma unroll
      for (int d = 0; d < DD; d++)
        acc = fma(Win64[(i*CD + c)*DD + d], r[d], acc);
      ze[c] = acc;
    }

    // ---- normalize (f64)
    double s0 = 0.0;
#pragma unroll
    for (int c = 0; c < CD; c++) s0 = fma(ze[c], ze[c], s0);
    double den = fmax(sqrt(s0), 1e-12);
    double enc[CD], s_enc = 0.0;
#pragma unroll
    for (int c = 0; c < CD; c++) {
      enc[c] = ze[c] / den;
      s_enc = fma(enc[c], enc[c], s_enc);
    }

    // ---- fast f32 search with best-2 tracking
    float encf[CD];
#pragma unroll
    for (int c = 0; c < CD; c++) encf[c] = (float)enc[c];
    const float s_encf = (float)s_enc;
    const float* __restrict__ cbni = cbn32 + i*KCB*CD;
    const float* __restrict__ si   = scbk32 + i*KCB;
    float best = 3.4e38f, best2 = 3.4e38f;
    int bidx = 0;
#pragma unroll 4
    for (int k = 0; k < KCB; k++) {
      float dot = encf[0] * cbni[k*CD];
#pragma unroll
      for (int c = 1; c < CD; c++)
        dot = fmaf(encf[c], cbni[k*CD + c], dot);
      float dist = fmaf(-2.f, dot, s_encf) + si[k];
      if (dist < best)       { best2 = best; best = dist; bidx = k; }
      else if (dist < best2) { best2 = dist; }
    }

    // ---- near-tie: authoritative f64 rescan (rare; exec-masked, wave skips if none)
    if (best2 - best < 1e-4f) {
      const double* __restrict__ cbni64 = cbn64 + i*KCB*CD;
      const double* __restrict__ si64   = scbk64 + i*KCB;
      double best64 = 1e300;
      bidx = 0;
      for (int k = 0; k < KCB; k++) {
        double dot = 0.0;
#pragma unroll
        for (int c = 0; c < CD; c++)
          dot = fma(enc[c], cbni64[k*CD + c], dot);
        double dist = s_enc - 2.0*dot + si64[k];
        if (dist < best64) { best64 = dist; bidx = k; }  // first-index tie-break
      }
    }

    // ---- gather raw codebook row (f32 values, exact in f64)
    double zq[CD];
#pragma unroll
    for (int c = 0; c < CD; c++) zq[c] = (double)cb[(i*KCB + bidx)*CD + c];

    // ---- losses (commit == cb_loss in forward value)
#pragma unroll
    for (int c = 0; c < CD; c++) {
      double dlt = ze[c] - zq[c];
      lacc = fma(dlt, dlt, lacc);
    }

    // ---- out_proj (f64) + residual update
#pragma unroll
    for (int d = 0; d < DD; d++) {
      double acc = bout64[i*DD + d];
#pragma unroll
      for (int c = 0; c < CD; c++)
        acc = fma(Wout64[(i*DD + d)*CD + c], zq[c], acc);
      r[d] -= acc;
    }

    // ---- codes (as float) and latents (= z_e)
    out[CODES_OFF + (b*NCB + i)*TT + t] = (float)bidx;
#pragma unroll
    for (int c = 0; c < CD; c++)
      out[LAT_OFF + (b*NCB*CD + i*CD + c)*TT + t] = (float)ze[c];
  }

  // ---- z_q = x - residual_final
#pragma unroll
  for (int d = 0; d < DD; d++)
    out[(b*DD + d)*TT + t] = (float)((double)x[(b*DD + d)*TT + t] - r[d]);

  // ---- deterministic loss reduction
#pragma unroll
  for (int off = 32; off > 0; off >>= 1)
    lacc += __shfl_down(lacc, off, 64);
  __shared__ double wsum[4];
  int wv = threadIdx.x >> 6;
  if ((threadIdx.x & 63) == 0) wsum[wv] = lacc;
  __syncthreads();
  if (threadIdx.x == 0)
    loss_part[blockIdx.x] = wsum[0] + wsum[1] + wsum[2] + wsum[3];
}

__global__ void loss_final(const double* __restrict__ loss_part,
                           float* __restrict__ out) {
  __shared__ double sh[256];
  double s = loss_part[threadIdx.x] + loss_part[threadIdx.x + 256];
  sh[threadIdx.x] = s;
  __syncthreads();
  for (int off = 128; off > 0; off >>= 1) {
    if (threadIdx.x < off) sh[threadIdx.x] += sh[threadIdx.x + off];
    __syncthreads();
  }
  if (threadIdx.x == 0) {
    double v = sh[0] / ((double)NCB * (double)BB * (double)CD * (double)TT);
    out[LOSS_OFF]     = (float)v;   // commit
    out[LOSS_OFF + 1] = (float)v;   // cb_loss (equal in forward value)
  }
}

extern "C" void kernel_launch(void* const* d_in, const int* in_sizes, int n_in,
                              void* d_out, int out_size, void* d_ws, size_t ws_size,
                              hipStream_t stream) {
  const float* x     = (const float*)d_in[0];
  const float* W_in  = (const float*)d_in[1];
  const float* b_in  = (const float*)d_in[2];
  const float* cb    = (const float*)d_in[3];
  const float* W_out = (const float*)d_in[4];
  const float* b_out = (const float*)d_in[5];
  float* out = (float*)d_out;

  char* ws = (char*)d_ws;
  float*  cbn32  = (float*)ws;
  float*  scbk32 = (float*)(ws + OFF_SCBK32);
  double* loss_part = (double*)(ws + OFF_LOSSPART);
  double* cbn64  = (double*)(ws + OFF_CBN64);
  double* scbk64 = (double*)(ws + OFF_SCBK64);
  double* Win64  = (double*)(ws + OFF_WIN64);
  double* Wout64 = (double*)(ws + OFF_WOUT64);
  double* bin64  = (double*)(ws + OFF_BIN64);
  double* bout64 = (double*)(ws + OFF_BOUT64);

  prep_cb<<<(NCB*KCB + 255)/256, 256, 0, stream>>>(cb, cbn32, scbk32, cbn64, scbk64);
  prep_w<<<(NCB*CD*DD + 255)/256, 256, 0, stream>>>(W_in, b_in, W_out, b_out,
                                                    Win64, bin64, Wout64, bout64);
  rvq_kernel<<<(BB*TT)/256, 256, 0, stream>>>(x, cb, Win64, bin64, Wout64, bout64,
                                              cbn32, scbk32, cbn64, scbk64,
                                              out, loss_part);
  loss_final<<<1, 256, 0, stream>>>(loss_part, out);
}

// Round 3
// 2052.543 us; speedup vs baseline: 1.2824x; 1.2824x over previous
//
#include <hip/hip_runtime.h>

#define NCB 9
#define KCB 1024
#define CD 8
#define DD 64
#define TT 32768
#define BB 4

#define ZQ_SZ (BB*DD*TT)              // 8388608
#define CODES_OFF ZQ_SZ
#define CODES_SZ (BB*NCB*TT)          // 1179648
#define LAT_OFF (CODES_OFF + CODES_SZ)
#define LAT_SZ (BB*NCB*CD*TT)         // 9437184
#define LOSS_OFF (LAT_OFF + LAT_SZ)   // 19005440

// ---- d_ws byte layout ----
#define OFF_CBN32    0          // 9216*8 f32      = 294912
#define OFF_CBN64    294912     // 9216*8 f64      = 589824
#define OFF_SCBK64   884736     // 9216 f64        = 73728
#define OFF_WIN64    958464     // 4608 f64        = 36864
#define OFF_WOUT64   995328     // 4608 f64        = 36864
#define OFF_BIN64    1032192    // 72 f64          = 576
#define OFF_BOUT64   1032768    // 576 f64         = 4608
#define OFF_LOSSPART 1037376    // 512 f64         = 4096

__global__ void prep_cb(const float* __restrict__ cb,
                        float* __restrict__ cbn32,
                        double* __restrict__ cbn64, double* __restrict__ scbk64) {
  int r = blockIdx.x * blockDim.x + threadIdx.x;
  if (r >= NCB * KCB) return;
  double v[CD], s = 0.0;
#pragma unroll
  for (int c = 0; c < CD; c++) { v[c] = (double)cb[r*CD + c]; s += v[c]*v[c]; }
  double den = fmax(sqrt(s), 1e-12);
  double s2 = 0.0;
#pragma unroll
  for (int c = 0; c < CD; c++) {
    double o = v[c] / den;
    cbn64[r*CD + c] = o;
    cbn32[r*CD + c] = (float)o;
    s2 += o*o;
  }
  scbk64[r] = s2;
}

__global__ void prep_w(const float* __restrict__ W_in, const float* __restrict__ b_in,
                       const float* __restrict__ W_out, const float* __restrict__ b_out,
                       double* __restrict__ Win64, double* __restrict__ bin64,
                       double* __restrict__ Wout64, double* __restrict__ bout64) {
  int i = blockIdx.x * blockDim.x + threadIdx.x;
  if (i < NCB*CD*DD) Win64[i]  = (double)W_in[i];
  if (i < NCB*CD*DD) Wout64[i] = (double)W_out[i];
  if (i < NCB*CD)    bin64[i]  = (double)b_in[i];
  if (i < NCB*DD)    bout64[i] = (double)b_out[i];
}

__global__ __launch_bounds__(256, 2) void rvq_kernel(
    const float* __restrict__ x,
    const float* __restrict__ cb,
    const double* __restrict__ Win64,
    const double* __restrict__ bin64,
    const double* __restrict__ Wout64,
    const double* __restrict__ bout64,
    const float* __restrict__ cbn32,
    const double* __restrict__ cbn64,
    const double* __restrict__ scbk64,
    float* __restrict__ out,
    double* __restrict__ loss_part) {
  const int tid = blockIdx.x * 256 + threadIdx.x;
  const int b = tid / TT;          // uniform per block (TT % 256 == 0)
  const int t = tid - b * TT;

  // residual chain in f64 — tracks the f64 golden reference end-to-end
  double r[DD];
#pragma unroll
  for (int d = 0; d < DD; d++) r[d] = (double)x[(b*DD + d)*TT + t];

  double lacc = 0.0;

#pragma unroll 1
  for (int i = 0; i < NCB; i++) {
    // ---- in_proj (f64): z_e = W_in[i] @ r + b_in[i]   (W uniform -> scalar loads)
    double ze[CD];
#pragma unroll
    for (int c = 0; c < CD; c++) ze[c] = bin64[i*CD + c];
#pragma unroll
    for (int c = 0; c < CD; c++) {
#pragma unroll
      for (int d = 0; d < DD; d++)
        ze[c] = fma(Win64[(i*CD + c)*DD + d], r[d], ze[c]);
    }

    // ---- normalize (f64): one true division, then multiply
    double s0 = 0.0;
#pragma unroll
    for (int c = 0; c < CD; c++) s0 = fma(ze[c], ze[c], s0);
    double den = fmax(sqrt(s0), 1e-12);
    double inv = 1.0 / den;
    double enc[CD], s_enc = 0.0;
#pragma unroll
    for (int c = 0; c < CD; c++) {
      enc[c] = ze[c] * inv;
      s_enc = fma(enc[c], enc[c], s_enc);
    }

    // ---- fast f32 search: maximize dot (codes are unit-norm: |s_k-1| <= 2.4e-7,
    // folded into the margin). Top-2 via med3/max, no select chain.
    float encf[CD];
#pragma unroll
    for (int c = 0; c < CD; c++) encf[c] = (float)enc[c];
    const float* __restrict__ cbni = cbn32 + i*KCB*CD;
    float best = -3.402823e38f, best2 = -3.402823e38f;
    int bidx = 0;
#pragma unroll 8
    for (int k = 0; k < KCB; k++) {
      float dot = encf[0] * cbni[k*CD];
#pragma unroll
      for (int c = 1; c < CD; c++)
        dot = fmaf(encf[c], cbni[k*CD + c], dot);
      float ob = best;
      best2 = __builtin_amdgcn_fmed3f(ob, best2, dot);   // 2nd-largest of {ob,best2,dot}
      best  = fmaxf(ob, dot);
      bidx  = (dot > ob) ? k : bidx;                     // strict > => first index on ties
    }

    // ---- near-tie: authoritative f64 rescan.
    // dot-gap margin 1.2e-5 vs total f32 key error <= ~3e-6 (4x safety).
    if (best - best2 < 1.2e-5f) {
      const double* __restrict__ cbni64 = cbn64 + i*KCB*CD;
      const double* __restrict__ si64   = scbk64 + i*KCB;
      double best64 = 1e300;
      int bi = 0;
#pragma unroll 4
      for (int k = 0; k < KCB; k++) {
        double dot = 0.0;
#pragma unroll
        for (int c = 0; c < CD; c++)
          dot = fma(enc[c], cbni64[k*CD + c], dot);
        double dist = fma(-2.0, dot, s_enc) + si64[k];
        if (dist < best64) { best64 = dist; bi = k; }    // first-index tie-break
      }
      bidx = bi;
    }

    // ---- gather raw codebook row (f32 values, exact in f64)
    const float4* __restrict__ qrow = (const float4*)(cb + (i*KCB + bidx)*CD);
    float4 q0 = qrow[0], q1 = qrow[1];
    double zq[CD] = {(double)q0.x, (double)q0.y, (double)q0.z, (double)q0.w,
                     (double)q1.x, (double)q1.y, (double)q1.z, (double)q1.w};

    // ---- losses (commit == cb_loss in forward value)
#pragma unroll
    for (int c = 0; c < CD; c++) {
      double dlt = ze[c] - zq[c];
      lacc = fma(dlt, dlt, lacc);
    }

    // ---- out_proj (f64) + residual update
#pragma unroll
    for (int d = 0; d < DD; d++) {
      double acc = bout64[i*DD + d];
#pragma unroll
      for (int c = 0; c < CD; c++)
        acc = fma(Wout64[(i*DD + d)*CD + c], zq[c], acc);
      r[d] -= acc;
    }

    // ---- codes (as float) and latents (= z_e)
    out[CODES_OFF + (b*NCB + i)*TT + t] = (float)bidx;
#pragma unroll
    for (int c = 0; c < CD; c++)
      out[LAT_OFF + (b*NCB*CD + i*CD + c)*TT + t] = (float)ze[c];
  }

  // ---- z_q = x - residual_final
#pragma unroll
  for (int d = 0; d < DD; d++)
    out[(b*DD + d)*TT + t] = (float)((double)x[(b*DD + d)*TT + t] - r[d]);

  // ---- deterministic loss reduction
#pragma unroll
  for (int off = 32; off > 0; off >>= 1)
    lacc += __shfl_down(lacc, off, 64);
  __shared__ double wsum[4];
  int wv = threadIdx.x >> 6;
  if ((threadIdx.x & 63) == 0) wsum[wv] = lacc;
  __syncthreads();
  if (threadIdx.x == 0)
    loss_part[blockIdx.x] = wsum[0] + wsum[1] + wsum[2] + wsum[3];
}

__global__ void loss_final(const double* __restrict__ loss_part,
                           float* __restrict__ out) {
  __shared__ double sh[256];
  double s = loss_part[threadIdx.x] + loss_part[threadIdx.x + 256];
  sh[threadIdx.x] = s;
  __syncthreads();
  for (int off = 128; off > 0; off >>= 1) {
    if (threadIdx.x < off) sh[threadIdx.x] += sh[threadIdx.x + off];
    __syncthreads();
  }
  if (threadIdx.x == 0) {
    double v = sh[0] / ((double)NCB * (double)BB * (double)CD * (double)TT);
    out[LOSS_OFF]     = (float)v;   // commit
    out[LOSS_OFF + 1] = (float)v;   // cb_loss (equal in forward value)
  }
}

extern "C" void kernel_launch(void* const* d_in, const int* in_sizes, int n_in,
                              void* d_out, int out_size, void* d_ws, size_t ws_size,
                              hipStream_t stream) {
  const float* x     = (const float*)d_in[0];
  const float* W_in  = (const float*)d_in[1];
  const float* b_in  = (const float*)d_in[2];
  const float* cb    = (const float*)d_in[3];
  const float* W_out = (const float*)d_in[4];
  const float* b_out = (const float*)d_in[5];
  float* out = (float*)d_out;

  char* ws = (char*)d_ws;
  float*  cbn32  = (float*)(ws + OFF_CBN32);
  double* cbn64  = (double*)(ws + OFF_CBN64);
  double* scbk64 = (double*)(ws + OFF_SCBK64);
  double* Win64  = (double*)(ws + OFF_WIN64);
  double* Wout64 = (double*)(ws + OFF_WOUT64);
  double* bin64  = (double*)(ws + OFF_BIN64);
  double* bout64 = (double*)(ws + OFF_BOUT64);
  double* loss_part = (double*)(ws + OFF_LOSSPART);

  prep_cb<<<(NCB*KCB + 255)/256, 256, 0, stream>>>(cb, cbn32, cbn64, scbk64);
  prep_w<<<(NCB*CD*DD + 255)/256, 256, 0, stream>>>(W_in, b_in, W_out, b_out,
                                                    Win64, bin64, Wout64, bout64);
  rvq_kernel<<<(BB*TT)/256, 256, 0, stream>>>(x, cb, Win64, bin64, Wout64, bout64,
                                              cbn32, cbn64, scbk64, out, loss_part);
  loss_final<<<1, 256, 0, stream>>>(loss_part, out);
}